// Round 11
// baseline (360.476 us; speedup 1.0000x reference)
//
#include <hip/hip_runtime.h>
#include <hip/hip_bf16.h>
#include <hip/hip_cooperative_groups.h>

namespace cg = cooperative_groups;

// Problem constants (B=1)
#define S_LEN 2048
#define E_DIM 1024
#define NH    16
#define HD    64
#define SM_SCALE 0.5f
#define SMEM_BYTES 43008   // max phase: attn 32768 (KV dbuf) + 10240 (P strips)

typedef short bf16x8_t  __attribute__((ext_vector_type(8)));    // 8 bf16 = 4 VGPRs
typedef float f32x4_t   __attribute__((ext_vector_type(4)));
typedef float f32x16_t  __attribute__((ext_vector_type(16)));
typedef __bf16 bf16x4_t __attribute__((ext_vector_type(4)));

static __device__ __forceinline__ unsigned short f2bf_bits(float f) {
    return __builtin_bit_cast(unsigned short, (__bf16)f);
}

// async global->LDS, 16B per lane, dest = wave-uniform base + lane*16
#define GLD16(gp, lp) __builtin_amdgcn_global_load_lds(                       \
    (const __attribute__((address_space(1))) void*)(gp),                      \
    (__attribute__((address_space(3))) void*)(lp), 16, 0, 0)

// ================= phase bodies (shared by mega-kernel and fallback) =======

// ---- prep: x fp32->bf16 (8 float4/thread) + W transpose->bf16 (16 tiles/blk)
__device__ __forceinline__ void prep_body(unsigned char* smem, int b,
    const float* __restrict__ x,
    const float* __restrict__ Wq, const float* __restrict__ Wk,
    const float* __restrict__ Wv, const float* __restrict__ Wo,
    __bf16* __restrict__ xb, __bf16* __restrict__ wt) {
    const int tid = threadIdx.x;
#pragma unroll
    for (int r = 0; r < 8; r++) {                  // 8*256*256 = 524288 float4 = all of x
        const int i = (r * 256 + b) * 256 + tid;
        const float4 v = ((const float4*)x)[i];
        bf16x4_t o4;
        o4.x = (__bf16)v.x; o4.y = (__bf16)v.y; o4.z = (__bf16)v.z; o4.w = (__bf16)v.w;
        ((bf16x4_t*)xb)[i] = o4;
    }
    float (*tile)[33] = (float(*)[33])smem;
    const int tx = tid & 31, ty = tid >> 5;        // ty 0..7
    for (int g = b; g < 4096; g += 256) {          // 4 W x 1024 32x32-tiles
        const int z = g >> 10, r = g & 1023;
        const int bx = (r & 31) * 32, by = (r >> 5) * 32;
        const float* W = z == 0 ? Wq : z == 1 ? Wk : z == 2 ? Wv : Wo;
        __bf16* o = wt + (size_t)z * E_DIM * E_DIM;
        __syncthreads();                           // prior tile's reads done
#pragma unroll
        for (int j = 0; j < 32; j += 8)
            tile[ty + j][tx] = W[(size_t)(by + ty + j) * E_DIM + bx + tx];
        __syncthreads();
#pragma unroll
        for (int j = 0; j < 32; j += 8)
            o[(size_t)(bx + ty + j) * E_DIM + by + tx] = (__bf16)tile[tx][ty + j];
    }
}

// ---- QKV: fused M=2048 x N=3072 GEMM, 64x192 tile, BK=32, double-buffered.
// Epilogue scatters into 32x32x16-MFMA operand-native layout (round-10 math).
__device__ __forceinline__ void qkv_body(unsigned char* smem, int bn, int bm,
    const __bf16* __restrict__ xb, const __bf16* __restrict__ wt,
    const float* __restrict__ bq, const float* __restrict__ bk, const float* __restrict__ bv,
    __bf16* __restrict__ qkv) {
    unsigned short (*As)[64 * 32]  = (unsigned short(*)[64 * 32])smem;
    unsigned short (*Bs)[192 * 32] = (unsigned short(*)[192 * 32])(smem + 8192);

    const int tid = threadIdx.x, w = tid >> 6, l = tid & 63;
    const int lm = l & 15, q4 = l >> 4;
    const int wm = w >> 1, wn = w & 1;     // wave: rows wm*32..+31, cols wn*96..+95

    const int sm = tid >> 2;
    const int skk = (tid & 3) << 3;
    const __bf16* Ag = xb + (size_t)(bm * 64 + sm) * E_DIM + skk;
    const __bf16* Bg = wt + (size_t)(bn * 192 + sm) * E_DIM + skk;
    const int woff = w << 9;

    f32x4_t acc[2][6];
#pragma unroll
    for (int i = 0; i < 2; i++)
#pragma unroll
        for (int j = 0; j < 6; j++) { acc[i][j].x = 0.f; acc[i][j].y = 0.f; acc[i][j].z = 0.f; acc[i][j].w = 0.f; }

    GLD16(Ag, &As[0][woff]);
#pragma unroll
    for (int g = 0; g < 3; g++)
        GLD16(Bg + (size_t)(g * 64) * E_DIM, &Bs[0][g * 2048 + woff]);
    __syncthreads();

    for (int s = 0; s < 32; s++) {
        const int bb = s & 1;
        if (s < 31) {
            const int k0 = (s + 1) * 32;
            GLD16(Ag + k0, &As[bb ^ 1][woff]);
#pragma unroll
            for (int g = 0; g < 3; g++)
                GLD16(Bg + (size_t)(g * 64) * E_DIM + k0, &Bs[bb ^ 1][g * 2048 + woff]);
        }
        bf16x8_t af[2], bfr[6];
#pragma unroll
        for (int mt = 0; mt < 2; mt++)
            af[mt] = *(const bf16x8_t*)&As[bb][(wm * 32 + mt * 16 + lm) * 32 + q4 * 8];
#pragma unroll
        for (int nt = 0; nt < 6; nt++)
            bfr[nt] = *(const bf16x8_t*)&Bs[bb][(wn * 96 + nt * 16 + lm) * 32 + q4 * 8];
#pragma unroll
        for (int mt = 0; mt < 2; mt++)
#pragma unroll
            for (int nt = 0; nt < 6; nt++)
                acc[mt][nt] = __builtin_amdgcn_mfma_f32_16x16x32_bf16(af[mt], bfr[nt], acc[mt][nt], 0, 0, 0);
        __syncthreads();
    }

#pragma unroll
    for (int nt = 0; nt < 6; nt++) {
        const int n = bn * 192 + wn * 96 + nt * 16 + lm;
        const int z = n >> 10, n10 = n & 1023;
        const float bval = (z == 0 ? bq : z == 1 ? bk : bv)[n10];
        const int h = n10 >> 6, d = n10 & 63;
        __bf16* out = qkv + (size_t)z * NH * S_LEN * HD;
        if (z == 2) {
            const int db = d >> 5, dl = d & 31;
#pragma unroll
            for (int mt = 0; mt < 2; mt++) {
                __bf16* ob = out + (((size_t)h * 32 + bm) * 8 + db * 4 + wm * 2 + mt) * 512
                                 + (dl + (q4 >> 1) * 32) * 8 + (q4 & 1) * 4;
                union { unsigned short s4[4]; uint2 u; } pk;
#pragma unroll
                for (int i = 0; i < 4; i++) pk.s4[i] = f2bf_bits(acc[mt][nt][i] + bval);
                *(uint2*)ob = pk.u;
            }
        } else {
            const float scale = (z == 0) ? SM_SCALE : 1.0f;   // fold SM_SCALE into Q (exact: pow2)
            const int kc = d >> 4, khalf = (d >> 3) & 1, j = d & 7;
#pragma unroll
            for (int mt = 0; mt < 2; mt++) {
                __bf16* ob = out + (((size_t)h * 32 + bm) * 8 + wm * 4 + kc) * 512
                                 + (mt * 16 + q4 * 4 + khalf * 32) * 8 + j;
#pragma unroll
                for (int i = 0; i < 4; i++)
                    ob[i * 8] = (__bf16)((acc[mt][nt][i] + bval) * scale);
            }
        }
    }
}

// ---- attention: 32x32x16 MFMA, 4 waves = (row-half rh) x (key-half kh),
// block b = (pair pi, head h); runs qt = pi then 31-pi -> exactly 33 kt-steps.
__device__ __forceinline__ void attn_body(unsigned char* smem, int b,
    const __bf16* __restrict__ Qf, const __bf16* __restrict__ Kf, const __bf16* __restrict__ Vf,
    __bf16* __restrict__ attn) {
    unsigned short (*KVs)[2][4096] = (unsigned short(*)[2][4096])smem;          // [buf][K/V]
    unsigned short (*Pl)[32 * 40]  = (unsigned short(*)[32 * 40])(smem + 32768);

    const int pi = b >> 4, h = b & 15;
    const int tid = threadIdx.x, w = tid >> 6, l = tid & 63;
    const int rh = w & 1, kh = w >> 1;
    const int l31 = l & 31, lh = l >> 5;

    const __bf16* Kb = Kf + (size_t)h * 32 * 4096;
    const __bf16* Vb = Vf + (size_t)h * 32 * 4096;
    unsigned short* Pw = Pl[w];

#pragma unroll
    for (int job = 0; job < 2; job++) {
        const int qt = job ? (31 - pi) : pi;
        const __bf16* Qb = Qf + ((size_t)h * 32 + qt) * 4096;

        bf16x8_t qf[4];
#pragma unroll
        for (int kc = 0; kc < 4; kc++)
            qf[kc] = *(const bf16x8_t*)(Qb + ((rh * 4 + kc) << 9) + l * 8);

        float lacc = 0.f;
        f32x16_t oacc[2];
#pragma unroll
        for (int db = 0; db < 2; db++)
#pragma unroll
            for (int r = 0; r < 16; r++) oacc[db][r] = 0.f;

        GLD16(Kb + (w << 9) + l * 8,       &KVs[0][0][(w << 9) + l * 8]);
        GLD16(Kb + ((w + 4) << 9) + l * 8, &KVs[0][0][((w + 4) << 9) + l * 8]);
        GLD16(Vb + (w << 9) + l * 8,       &KVs[0][1][(w << 9) + l * 8]);
        GLD16(Vb + ((w + 4) << 9) + l * 8, &KVs[0][1][((w + 4) << 9) + l * 8]);
        __syncthreads();

        for (int s = 0; s <= qt; s++) {
            const int bb = s & 1;
            if (s < qt) {
                const __bf16* Kg = Kb + (size_t)(s + 1) * 4096;
                const __bf16* Vg = Vb + (size_t)(s + 1) * 4096;
                GLD16(Kg + (w << 9) + l * 8,       &KVs[bb ^ 1][0][(w << 9) + l * 8]);
                GLD16(Kg + ((w + 4) << 9) + l * 8, &KVs[bb ^ 1][0][((w + 4) << 9) + l * 8]);
                GLD16(Vg + (w << 9) + l * 8,       &KVs[bb ^ 1][1][(w << 9) + l * 8]);
                GLD16(Vg + ((w + 4) << 9) + l * 8, &KVs[bb ^ 1][1][((w + 4) << 9) + l * 8]);
            }
            const bool diag = (s == qt);
            if (!(diag && kh > rh)) {
                f32x16_t st;
#pragma unroll
                for (int r = 0; r < 16; r++) st[r] = 0.f;
#pragma unroll
                for (int kc = 0; kc < 4; kc++) {
                    bf16x8_t kf = *(const bf16x8_t*)&KVs[bb][0][((kh * 4 + kc) << 9) + l * 8];
                    st = __builtin_amdgcn_mfma_f32_32x32x16_bf16(kf, qf[kc], st, 0, 0, 0);
                }
                if (diag && kh == rh) {
#pragma unroll
                    for (int r = 0; r < 16; r++) {
                        const int keyl = (r & 3) + 8 * (r >> 2) + 4 * lh;
                        st[r] = (keyl > l31) ? 0.f : __expf(st[r]);
                    }
                } else {
#pragma unroll
                    for (int r = 0; r < 16; r++) st[r] = __expf(st[r]);
                }
#pragma unroll
                for (int r = 0; r < 16; r++) lacc += st[r];
#pragma unroll
                for (int a = 0; a < 4; a++) {
                    union { unsigned short s4[4]; uint2 u; } pk;
#pragma unroll
                    for (int i = 0; i < 4; i++) pk.s4[i] = f2bf_bits(st[a * 4 + i]);
                    *(uint2*)&Pw[l31 * 40 + lh * 4 + a * 8] = pk.u;
                }
#pragma unroll
                for (int c = 0; c < 2; c++) {
                    bf16x8_t pf = *(const bf16x8_t*)&Pw[l31 * 40 + c * 16 + lh * 8];
#pragma unroll
                    for (int db = 0; db < 2; db++) {
                        bf16x8_t vf = *(const bf16x8_t*)&KVs[bb][1][((db * 4 + kh * 2 + c) << 9) + l * 8];
                        oacc[db] = __builtin_amdgcn_mfma_f32_32x32x16_bf16(vf, pf, oacc[db], 0, 0, 0);
                    }
                }
            }
            __syncthreads();
        }

        float* Ex = (float*)smem;               // reuse KV region: [rh*64+lane][34]
        if (kh == 1) {
            float* e = Ex + (rh * 64 + l) * 34;
#pragma unroll
            for (int db = 0; db < 2; db++)
#pragma unroll
                for (int r = 0; r < 16; r++) e[db * 16 + r] = oacc[db][r];
            e[32] = lacc;
        }
        __syncthreads();
        if (kh == 0) {
            const float* e = Ex + (rh * 64 + l) * 34;
#pragma unroll
            for (int db = 0; db < 2; db++)
#pragma unroll
                for (int r = 0; r < 16; r++) oacc[db][r] += e[db * 16 + r];
            lacc += e[32];
            lacc += __shfl_xor(lacc, 32, 64);
            const float rl = 1.f / lacc;
            const int row = qt * 64 + rh * 32 + l31;
#pragma unroll
            for (int db = 0; db < 2; db++)
#pragma unroll
                for (int a = 0; a < 4; a++) {
                    union { unsigned short s4[4]; uint2 u; } pk;
#pragma unroll
                    for (int i = 0; i < 4; i++) pk.s4[i] = f2bf_bits(oacc[db][a * 4 + i] * rl);
                    *(uint2*)(attn + (size_t)row * E_DIM + h * HD + db * 32 + a * 8 + lh * 4) = pk.u;
                }
        }
        __syncthreads();
    }
}

// ---- output projection: 64x128 tile, double-buffered staging
__device__ __forceinline__ void out_body(unsigned char* smem, int bn, int bm,
    const __bf16* __restrict__ A, const __bf16* __restrict__ Bt,
    const float* __restrict__ bias, float* __restrict__ out) {
    unsigned short (*As)[64 * 32]  = (unsigned short(*)[64 * 32])smem;
    unsigned short (*Bs)[128 * 32] = (unsigned short(*)[128 * 32])(smem + 8192);

    const int tid = threadIdx.x, w = tid >> 6, l = tid & 63;
    const int lm = l & 15, q4 = l >> 4;
    const int wm = w >> 1, wn = w & 1;

    const int sm = (w << 4) + (l >> 2);
    const int skk = (l & 3) << 3;
    const __bf16* Ag = A + (size_t)(bm * 64 + sm) * E_DIM + skk;
    const __bf16* Bg = Bt + (size_t)(bn * 128 + sm) * E_DIM + skk;
    const int woff = w << 9;

    f32x4_t acc[2][4];
#pragma unroll
    for (int i = 0; i < 2; i++)
#pragma unroll
        for (int j = 0; j < 4; j++) { acc[i][j].x = 0.f; acc[i][j].y = 0.f; acc[i][j].z = 0.f; acc[i][j].w = 0.f; }

    GLD16(Ag, &As[0][woff]);
    GLD16(Bg, &Bs[0][woff]);
    GLD16(Bg + (size_t)64 * E_DIM, &Bs[0][woff + 2048]);
    __syncthreads();

    for (int s = 0; s < 32; s++) {
        const int bb = s & 1;
        if (s < 31) {
            const int k0 = (s + 1) * 32;
            GLD16(Ag + k0, &As[bb ^ 1][woff]);
            GLD16(Bg + k0, &Bs[bb ^ 1][woff]);
            GLD16(Bg + (size_t)64 * E_DIM + k0, &Bs[bb ^ 1][woff + 2048]);
        }
        bf16x8_t af[2], bfr[4];
#pragma unroll
        for (int mt = 0; mt < 2; mt++)
            af[mt] = *(const bf16x8_t*)&As[bb][(wm * 32 + mt * 16 + lm) * 32 + q4 * 8];
#pragma unroll
        for (int nt = 0; nt < 4; nt++)
            bfr[nt] = *(const bf16x8_t*)&Bs[bb][(wn * 64 + nt * 16 + lm) * 32 + q4 * 8];
#pragma unroll
        for (int mt = 0; mt < 2; mt++)
#pragma unroll
            for (int nt = 0; nt < 4; nt++)
                acc[mt][nt] = __builtin_amdgcn_mfma_f32_16x16x32_bf16(af[mt], bfr[nt], acc[mt][nt], 0, 0, 0);
        __syncthreads();
    }

#pragma unroll
    for (int nt = 0; nt < 4; nt++) {
        const int n = bn * 128 + wn * 64 + nt * 16 + lm;
        const float bval = bias[n];
#pragma unroll
        for (int mt = 0; mt < 2; mt++) {
            const int r0 = bm * 64 + wm * 32 + mt * 16 + q4 * 4;
#pragma unroll
            for (int i = 0; i < 4; i++)
                out[(size_t)(r0 + i) * E_DIM + n] = acc[mt][nt][i] + bval;
        }
    }
}

// ================= mega-kernel (cooperative) ==============================
__global__ __launch_bounds__(256) void k_mega(
    const float* __restrict__ x,
    const float* __restrict__ Wq, const float* __restrict__ Wk,
    const float* __restrict__ Wv, const float* __restrict__ Wo,
    const float* __restrict__ bq, const float* __restrict__ bk,
    const float* __restrict__ bv, const float* __restrict__ bo,
    __bf16* __restrict__ xb, __bf16* __restrict__ wt,
    __bf16* __restrict__ qkv, __bf16* __restrict__ attn, float* __restrict__ out) {
    __shared__ __align__(16) unsigned char smem[SMEM_BYTES];
    cg::grid_group grid = cg::this_grid();
    const int b = blockIdx.x;

    prep_body(smem, b, x, Wq, Wk, Wv, Wo, xb, wt);
    __threadfence();
    grid.sync();

    qkv_body(smem, b & 15, b >> 4, xb, wt, bq, bk, bv, qkv);
    __syncthreads();
    qkv_body(smem, b & 15, 16 + (b >> 4), xb, wt, bq, bk, bv, qkv);
    __threadfence();
    grid.sync();

    attn_body(smem, b, qkv, qkv + (size_t)NH * S_LEN * HD,
              qkv + (size_t)2 * NH * S_LEN * HD, attn);
    __threadfence();
    grid.sync();

    out_body(smem, b & 7, b >> 3, attn, wt + (size_t)3 * E_DIM * E_DIM, bo, out);
}

// ================= fallback standalone kernels ============================
__global__ __launch_bounds__(256) void k_prep_s(
    const float* x, const float* Wq, const float* Wk, const float* Wv, const float* Wo,
    __bf16* xb, __bf16* wt) {
    __shared__ __align__(16) unsigned char smem[4224];
    prep_body(smem, blockIdx.x, x, Wq, Wk, Wv, Wo, xb, wt);
}
__global__ __launch_bounds__(256) void k_qkv_s(
    const __bf16* xb, const __bf16* wt,
    const float* bq, const float* bk, const float* bv, __bf16* qkv) {
    __shared__ __align__(16) unsigned char smem[32768];
    qkv_body(smem, blockIdx.x & 15, blockIdx.x >> 4, xb, wt, bq, bk, bv, qkv);
}
__global__ __launch_bounds__(256, 2) void k_attn_s(
    const __bf16* Qf, const __bf16* Kf, const __bf16* Vf, __bf16* attn) {
    __shared__ __align__(16) unsigned char smem[SMEM_BYTES];
    attn_body(smem, blockIdx.x, Qf, Kf, Vf, attn);
}
__global__ __launch_bounds__(256) void k_out_s(
    const __bf16* A, const __bf16* Bt, const float* bias, float* out) {
    __shared__ __align__(16) unsigned char smem[24576];
    out_body(smem, blockIdx.x & 7, blockIdx.x >> 3, A, Bt, bias, out);
}

extern "C" void kernel_launch(void* const* d_in, const int* in_sizes, int n_in,
                              void* d_out, int out_size, void* d_ws, size_t ws_size,
                              hipStream_t stream) {
    const float* x  = (const float*)d_in[0];
    const float* Wq = (const float*)d_in[1];
    const float* bq = (const float*)d_in[2];
    const float* Wk = (const float*)d_in[3];
    const float* bk = (const float*)d_in[4];
    const float* Wv = (const float*)d_in[5];
    const float* bv = (const float*)d_in[6];
    const float* Wo = (const float*)d_in[7];
    const float* bo = (const float*)d_in[8];
    float* out = (float*)d_out;

    char* ws = (char*)d_ws;
    __bf16* xb   = (__bf16*)(ws);                        // 4 MB  x bf16 [S][E]
    __bf16* wt   = (__bf16*)(ws + ((size_t)4  << 20));   // 4x2MB [Wq^T,Wk^T,Wv^T,Wo^T] bf16
    __bf16* qkv  = (__bf16*)(ws + ((size_t)12 << 20));   // op-native Qf,Kf,Vf (4MB each)
    __bf16* attn = (__bf16*)(ws + ((size_t)24 << 20));   // 4 MB  [S][E] bf16

    void* args[] = {
        (void*)&x, (void*)&Wq, (void*)&Wk, (void*)&Wv, (void*)&Wo,
        (void*)&bq, (void*)&bk, (void*)&bv, (void*)&bo,
        (void*)&xb, (void*)&wt, (void*)&qkv, (void*)&attn, (void*)&out
    };
    hipError_t err = hipLaunchCooperativeKernel((const void*)k_mega,
                                                dim3(256), dim3(256), args, 0, stream);
    if (err != hipSuccess) {
        // fallback: same bodies, 4 launches (deterministic across calls)
        k_prep_s<<<dim3(256), 256, 0, stream>>>(x, Wq, Wk, Wv, Wo, xb, wt);
        k_qkv_s<<<dim3(512), 256, 0, stream>>>(xb, wt, bq, bk, bv, qkv);
        k_attn_s<<<dim3(256), 256, 0, stream>>>(
            qkv, qkv + (size_t)NH * S_LEN * HD, qkv + (size_t)2 * NH * S_LEN * HD, attn);
        k_out_s<<<dim3(256), 256, 0, stream>>>(
            attn, wt + (size_t)3 * E_DIM * E_DIM, bo, out);
    }
}

// Round 12
// 154.259 us; speedup vs baseline: 2.3368x; 2.3368x over previous
//
#include <hip/hip_runtime.h>
#include <hip/hip_bf16.h>

// Problem constants (B=1)
#define S_LEN 2048
#define E_DIM 1024
#define NH    16
#define HD    64
#define SM_SCALE 0.5f

typedef short bf16x8_t  __attribute__((ext_vector_type(8)));    // 8 bf16 = 4 VGPRs
typedef float f32x4_t   __attribute__((ext_vector_type(4)));
typedef float f32x16_t  __attribute__((ext_vector_type(16)));
typedef __bf16 bf16x4_t __attribute__((ext_vector_type(4)));

static __device__ __forceinline__ unsigned short f2bf_bits(float f) {
    return __builtin_bit_cast(unsigned short, (__bf16)f);
}

// async global->LDS, 16B per lane, dest = wave-uniform base + lane*16
#define GLD16(gp, lp) __builtin_amdgcn_global_load_lds(                       \
    (const __attribute__((address_space(1))) void*)(gp),                      \
    (__attribute__((address_space(3))) void*)(lp), 16, 0, 0)

// -------------------------------------------- merged prep: W^T + x->bf16
__global__ void k_prep(const float* __restrict__ x,
                       const float* __restrict__ Wq, const float* __restrict__ Wk,
                       const float* __restrict__ Wv, const float* __restrict__ Wo,
                       __bf16* __restrict__ xb, __bf16* __restrict__ wt) {
    const int z = blockIdx.z;
    if (z < 4) {
        __shared__ float tile[32][33];
        const float* W = z == 0 ? Wq : z == 1 ? Wk : z == 2 ? Wv : Wo;
        __bf16* o = wt + (size_t)z * E_DIM * E_DIM;
        const int tx = threadIdx.x, ty = threadIdx.y;
        const int bx = blockIdx.x * 32, by = blockIdx.y * 32;
#pragma unroll
        for (int j = 0; j < 32; j += 8)
            tile[ty + j][tx] = W[(size_t)(by + ty + j) * E_DIM + bx + tx];
        __syncthreads();
#pragma unroll
        for (int j = 0; j < 32; j += 8)
            o[(size_t)(bx + ty + j) * E_DIM + by + tx] = (__bf16)tile[tx][ty + j];
    } else {
        const int bid = (z - 4) * 1024 + blockIdx.y * 32 + blockIdx.x;
        const int tid = threadIdx.y * 32 + threadIdx.x;
        const int i = bid * 256 + tid;
        const float4 v = ((const float4*)x)[i];
        bf16x4_t o4;
        o4.x = (__bf16)v.x; o4.y = (__bf16)v.y; o4.z = (__bf16)v.z; o4.w = (__bf16)v.w;
        ((bf16x4_t*)xb)[i] = o4;
    }
}

// ------------------------------------------------------- QKV projection GEMM
// 128x128 tile, BK=32 (m97 structure). Epilogue scatters into 32x32x16-MFMA
// operand-native layout (A/B layout: [m|n=lane&31][k=(lane>>5)*8+j]):
//   Q (B-op): [h][qt][rb2][kc4][lane64][j8]  rb=(s&63)>>5, lane=(s&31)+((d>>3)&1)*32, kc=d>>4, j=d&7
//   K (A-op): same index function as Q
//   V (A-op, V^T): [h][kt][db2][kc4][lane64][j8] db=d>>5, lane=(d&31)+((key>>3)&1)*32, kc=(key&63)>>4, j=key&7
__global__ __launch_bounds__(256) void k_gemm_qkv(
    const __bf16* __restrict__ xb, const __bf16* __restrict__ wt,
    const float* __restrict__ bq, const float* __restrict__ bk, const float* __restrict__ bv,
    __bf16* __restrict__ qkv) {
    __shared__ __align__(16) unsigned short As[128 * 32];
    __shared__ __align__(16) unsigned short Bs[128 * 32];

    const int z = blockIdx.z;
    const __bf16* Bt = wt + (size_t)z * E_DIM * E_DIM;      // W^T [n][k]
    const float* bias = z == 0 ? bq : z == 1 ? bk : bv;
    __bf16* out = qkv + (size_t)z * NH * S_LEN * HD;

    const int tid = threadIdx.x, w = tid >> 6, l = tid & 63;
    const int lm = l & 15, q4 = l >> 4;
    const int bm = blockIdx.y, bn = blockIdx.x;
    const int wm = w >> 1, wn = w & 1;

    const int sm = (w << 4) + (l >> 2);
    const int skk = (l & 3) << 3;
    const __bf16* Ag = xb + (size_t)(bm * 128 + sm) * E_DIM + skk;
    const __bf16* Bg = Bt + (size_t)(bn * 128 + sm) * E_DIM + skk;
    unsigned short* AsW = As + (w << 9);
    unsigned short* BsW = Bs + (w << 9);

    f32x4_t acc[4][4];
#pragma unroll
    for (int i = 0; i < 4; i++)
#pragma unroll
        for (int j = 0; j < 4; j++) { acc[i][j].x = 0.f; acc[i][j].y = 0.f; acc[i][j].z = 0.f; acc[i][j].w = 0.f; }

    for (int k0 = 0; k0 < E_DIM; k0 += 32) {
        __syncthreads();
        GLD16(Ag + k0, AsW);
        GLD16(Ag + (size_t)64 * E_DIM + k0, AsW + 2048);
        GLD16(Bg + k0, BsW);
        GLD16(Bg + (size_t)64 * E_DIM + k0, BsW + 2048);
        __syncthreads();

        bf16x8_t af[4], bfr[4];
#pragma unroll
        for (int mt = 0; mt < 4; mt++)
            af[mt] = *(const bf16x8_t*)&As[(wm * 64 + mt * 16 + lm) * 32 + q4 * 8];
#pragma unroll
        for (int nt = 0; nt < 4; nt++)
            bfr[nt] = *(const bf16x8_t*)&Bs[(wn * 64 + nt * 16 + lm) * 32 + q4 * 8];
#pragma unroll
        for (int mt = 0; mt < 4; mt++)
#pragma unroll
            for (int nt = 0; nt < 4; nt++)
                acc[mt][nt] = __builtin_amdgcn_mfma_f32_16x16x32_bf16(af[mt], bfr[nt], acc[mt][nt], 0, 0, 0);
    }

    // C row s = bm*128 + wm*64 + mt*16 + q4*4 + i ; col n = bn*128 + wn*64 + nt*16 + lm
#pragma unroll
    for (int nt = 0; nt < 4; nt++) {
        const int n = bn * 128 + wn * 64 + nt * 16 + lm;
        const float bval = bias[n];
        const int h = n >> 6, d = n & 63;
        const int tile0 = bm * 2 + wm;          // s>>6
        if (z == 2) {
            // V A-op-native: key = mt*16 + q4*4 + i (local in tile)
            const int db = d >> 5, dl = d & 31;
#pragma unroll
            for (int mt = 0; mt < 4; mt++) {
                __bf16* ob = out + (((size_t)h * 32 + tile0) * 8 + db * 4 + mt) * 512
                                 + (dl + (q4 >> 1) * 32) * 8 + (q4 & 1) * 4;
                union { unsigned short s4[4]; uint2 u; } pk;
#pragma unroll
                for (int i = 0; i < 4; i++) pk.s4[i] = f2bf_bits(acc[mt][nt][i] + bval);
                *(uint2*)ob = pk.u;
            }
        } else {
            // Q/K op-native: s_local = mt*16 + q4*4 + i, rb = mt>>1
            const float scale = (z == 0) ? SM_SCALE : 1.0f;   // fold SM_SCALE into Q (exact: pow2)
            const int kc = d >> 4, khalf = (d >> 3) & 1, j = d & 7;
#pragma unroll
            for (int mt = 0; mt < 4; mt++) {
                __bf16* ob = out + (((size_t)h * 32 + tile0) * 8 + (mt >> 1) * 4 + kc) * 512
                                 + ((mt & 1) * 16 + q4 * 4 + khalf * 32) * 8 + j;
#pragma unroll
                for (int i = 0; i < 4; i++)
                    ob[i * 8] = (__bf16)((acc[mt][nt][i] + bval) * scale);
            }
        }
    }
}

// ------------------------------------------------------------- attention
// 32x32x16 MFMA. 4 waves = (row-half rh = w&1) x (key-half kh = w>>1).
// Wave (rh,kh): S^T(32k x 32r) = K_kh · Q_rh^T in 4 MFMA (4 kf b128 reads),
// O^T(64d x 32r) += V^T·P in 4 MFMA (4 vf + 2 pf reads). Key-half partials
// combine linearly at end (no-max softmax, scores bounded). K/V tiles
// double-buffered via GLD16.
__global__ __launch_bounds__(256, 2) void k_attn(
    const __bf16* __restrict__ Qf, const __bf16* __restrict__ Kf, const __bf16* __restrict__ Vf,
    __bf16* __restrict__ attn) {
    __shared__ __align__(16) unsigned short KVs[2][2][4096];  // [buf][K/V][8KB tile]
    __shared__ __align__(16) unsigned short Pl[4][32 * 40];   // per-wave P [row][key] pad 40

    // work-balanced swizzle: long q-tiles dispatched first
    const int b = blockIdx.x;
    int qt, h;
    if (b < 256) { qt = 16 + (b >> 4); h = b & 15; }
    else         { qt = 15 - ((b - 256) >> 4); h = (b - 256) & 15; }

    const int tid = threadIdx.x, w = tid >> 6, l = tid & 63;
    const int rh = w & 1, kh = w >> 1;
    const int l31 = l & 31, lh = l >> 5;

    const __bf16* Qb = Qf + ((size_t)h * 32 + qt) * 4096;
    const __bf16* Kb = Kf + (size_t)h * 32 * 4096;
    const __bf16* Vb = Vf + (size_t)h * 32 * 4096;

    // Q B-frags pinned (pre-scaled by SM_SCALE): rows rh*32..+31, 4 k-chunks
    bf16x8_t qf[4];
#pragma unroll
    for (int kc = 0; kc < 4; kc++)
        qf[kc] = *(const bf16x8_t*)(Qb + ((rh * 4 + kc) << 9) + l * 8);

    float lacc = 0.f;
    f32x16_t oacc[2];
#pragma unroll
    for (int db = 0; db < 2; db++)
#pragma unroll
        for (int r = 0; r < 16; r++) oacc[db][r] = 0.f;

    unsigned short* Pw = Pl[w];

    // prologue: stage tile 0 into buf 0 (wave w: chunks w, w+4 of K and V)
    GLD16(Kb + (w << 9) + l * 8,       &KVs[0][0][(w << 9) + l * 8]);
    GLD16(Kb + ((w + 4) << 9) + l * 8, &KVs[0][0][((w + 4) << 9) + l * 8]);
    GLD16(Vb + (w << 9) + l * 8,       &KVs[0][1][(w << 9) + l * 8]);
    GLD16(Vb + ((w + 4) << 9) + l * 8, &KVs[0][1][((w + 4) << 9) + l * 8]);
    __syncthreads();

    for (int s = 0; s <= qt; s++) {
        const int bb = s & 1;
        if (s < qt) {   // prefetch next tile into the other buffer
            const __bf16* Kg = Kb + (size_t)(s + 1) * 4096;
            const __bf16* Vg = Vb + (size_t)(s + 1) * 4096;
            GLD16(Kg + (w << 9) + l * 8,       &KVs[bb ^ 1][0][(w << 9) + l * 8]);
            GLD16(Kg + ((w + 4) << 9) + l * 8, &KVs[bb ^ 1][0][((w + 4) << 9) + l * 8]);
            GLD16(Vg + (w << 9) + l * 8,       &KVs[bb ^ 1][1][(w << 9) + l * 8]);
            GLD16(Vg + ((w + 4) << 9) + l * 8, &KVs[bb ^ 1][1][((w + 4) << 9) + l * 8]);
        }

        const bool diag = (s == qt);
        if (!(diag && kh > rh)) {          // (rh=0,kh=1) diag block fully masked
            // S^T = K·Q^T : D[key = (reg&3)+8*(reg>>2)+4*lh][row = l31]
            f32x16_t st;
#pragma unroll
            for (int r = 0; r < 16; r++) st[r] = 0.f;
#pragma unroll
            for (int kc = 0; kc < 4; kc++) {
                bf16x8_t kf = *(const bf16x8_t*)&KVs[bb][0][((kh * 4 + kc) << 9) + l * 8];
                st = __builtin_amdgcn_mfma_f32_32x32x16_bf16(kf, qf[kc], st, 0, 0, 0);
            }
            // exp (+ causal mask only on the diagonal kh==rh block)
            if (diag && kh == rh) {
#pragma unroll
                for (int r = 0; r < 16; r++) {
                    const int keyl = (r & 3) + 8 * (r >> 2) + 4 * lh;
                    st[r] = (keyl > l31) ? 0.f : __expf(st[r]);
                }
            } else {
#pragma unroll
                for (int r = 0; r < 16; r++) st[r] = __expf(st[r]);
            }
#pragma unroll
            for (int r = 0; r < 16; r++) lacc += st[r];
            // P write: reg-quad a holds keys 8a+4lh+[0..3] for row l31 -> b64
#pragma unroll
            for (int a = 0; a < 4; a++) {
                union { unsigned short s4[4]; uint2 u; } pk;
#pragma unroll
                for (int i = 0; i < 4; i++) pk.s4[i] = f2bf_bits(st[a * 4 + i]);
                *(uint2*)&Pw[l31 * 40 + lh * 4 + a * 8] = pk.u;
            }
            // O^T += V^T·P : A = V frags, B = P frags (keys kh*32 + c*16 + lh*8 + j)
#pragma unroll
            for (int c = 0; c < 2; c++) {
                bf16x8_t pf = *(const bf16x8_t*)&Pw[l31 * 40 + c * 16 + lh * 8];
#pragma unroll
                for (int db = 0; db < 2; db++) {
                    bf16x8_t vf = *(const bf16x8_t*)&KVs[bb][1][((db * 4 + kh * 2 + c) << 9) + l * 8];
                    oacc[db] = __builtin_amdgcn_mfma_f32_32x32x16_bf16(vf, pf, oacc[db], 0, 0, 0);
                }
            }
        }
        __syncthreads();   // reads of buf bb done; prefetch of bb^1 landed
    }

    // ---- key-half combine (linear: no-max softmax) ----
    __syncthreads();                        // KVs reusable as exchange space
    float* Ex = (float*)KVs;                // [rh*64 + lane][34]: 32 O + lacc
    if (kh == 1) {
        float* e = Ex + (rh * 64 + l) * 34;
#pragma unroll
        for (int db = 0; db < 2; db++)
#pragma unroll
            for (int r = 0; r < 16; r++) e[db * 16 + r] = oacc[db][r];
        e[32] = lacc;
    }
    __syncthreads();
    if (kh == 0) {
        const float* e = Ex + (rh * 64 + l) * 34;
#pragma unroll
        for (int db = 0; db < 2; db++)
#pragma unroll
            for (int r = 0; r < 16; r++) oacc[db][r] += e[db * 16 + r];
        lacc += e[32];
        lacc += __shfl_xor(lacc, 32, 64);   // lanes l31 / l31+32 hold same row
        const float rl = 1.f / lacc;
        const int row = qt * 64 + rh * 32 + l31;
#pragma unroll
        for (int db = 0; db < 2; db++)
#pragma unroll
            for (int a = 0; a < 4; a++) {
                union { unsigned short s4[4]; uint2 u; } pk;
#pragma unroll
                for (int i = 0; i < 4; i++) pk.s4[i] = f2bf_bits(oacc[db][a * 4 + i] * rl);
                *(uint2*)(attn + (size_t)row * E_DIM + h * HD + db * 32 + a * 8 + lh * 4) = pk.u;
            }
    }
}

// --------------------------------------------------------- output projection
// 64x128 tile, double-buffered LDS staging (1 block/CU -> latency exposed).
__global__ __launch_bounds__(256) void k_gemm_out(
    const __bf16* __restrict__ A, const __bf16* __restrict__ Bt,
    const float* __restrict__ bias, float* __restrict__ out) {
    __shared__ __align__(16) unsigned short As[2][64 * 32];
    __shared__ __align__(16) unsigned short Bs[2][128 * 32];

    const int tid = threadIdx.x, w = tid >> 6, l = tid & 63;
    const int lm = l & 15, q4 = l >> 4;
    const int bm = blockIdx.y, bn = blockIdx.x;
    const int wm = w >> 1, wn = w & 1;

    const int sm = (w << 4) + (l >> 2);
    const int skk = (l & 3) << 3;
    const __bf16* Ag = A + (size_t)(bm * 64 + sm) * E_DIM + skk;
    const __bf16* Bg = Bt + (size_t)(bn * 128 + sm) * E_DIM + skk;
    const int woff = w << 9;

    f32x4_t acc[2][4];
#pragma unroll
    for (int i = 0; i < 2; i++)
#pragma unroll
        for (int j = 0; j < 4; j++) { acc[i][j].x = 0.f; acc[i][j].y = 0.f; acc[i][j].z = 0.f; acc[i][j].w = 0.f; }

    GLD16(Ag, &As[0][woff]);
    GLD16(Bg, &Bs[0][woff]);
    GLD16(Bg + (size_t)64 * E_DIM, &Bs[0][woff + 2048]);
    __syncthreads();

    for (int s = 0; s < 32; s++) {
        const int bb = s & 1;
        if (s < 31) {
            const int k0 = (s + 1) * 32;
            GLD16(Ag + k0, &As[bb ^ 1][woff]);
            GLD16(Bg + k0, &Bs[bb ^ 1][woff]);
            GLD16(Bg + (size_t)64 * E_DIM + k0, &Bs[bb ^ 1][woff + 2048]);
        }

        bf16x8_t af[2], bfr[4];
#pragma unroll
        for (int mt = 0; mt < 2; mt++)
            af[mt] = *(const bf16x8_t*)&As[bb][(wm * 32 + mt * 16 + lm) * 32 + q4 * 8];
#pragma unroll
        for (int nt = 0; nt < 4; nt++)
            bfr[nt] = *(const bf16x8_t*)&Bs[bb][(wn * 64 + nt * 16 + lm) * 32 + q4 * 8];
#pragma unroll
        for (int mt = 0; mt < 2; mt++)
#pragma unroll
            for (int nt = 0; nt < 4; nt++)
                acc[mt][nt] = __builtin_amdgcn_mfma_f32_16x16x32_bf16(af[mt], bfr[nt], acc[mt][nt], 0, 0, 0);
        __syncthreads();
    }

#pragma unroll
    for (int nt = 0; nt < 4; nt++) {
        const int n = bn * 128 + wn * 64 + nt * 16 + lm;
        const float bval = bias[n];
#pragma unroll
        for (int mt = 0; mt < 2; mt++) {
            const int r0 = bm * 64 + wm * 32 + mt * 16 + q4 * 4;
#pragma unroll
            for (int i = 0; i < 4; i++)
                out[(size_t)(r0 + i) * E_DIM + n] = acc[mt][nt][i] + bval;
        }
    }
}

extern "C" void kernel_launch(void* const* d_in, const int* in_sizes, int n_in,
                              void* d_out, int out_size, void* d_ws, size_t ws_size,
                              hipStream_t stream) {
    const float* x  = (const float*)d_in[0];
    const float* Wq = (const float*)d_in[1];
    const float* bq = (const float*)d_in[2];
    const float* Wk = (const float*)d_in[3];
    const float* bk = (const float*)d_in[4];
    const float* Wv = (const float*)d_in[5];
    const float* bv = (const float*)d_in[6];
    const float* Wo = (const float*)d_in[7];
    const float* bo = (const float*)d_in[8];
    float* out = (float*)d_out;

    char* ws = (char*)d_ws;
    __bf16* xb   = (__bf16*)(ws);                        // 4 MB  x bf16 [S][E]
    __bf16* wt   = (__bf16*)(ws + ((size_t)4  << 20));   // 4x2MB [Wq^T,Wk^T,Wv^T,Wo^T] bf16
    __bf16* qkv  = (__bf16*)(ws + ((size_t)12 << 20));   // op-native Qf,Kf,Vf (4MB each)
    __bf16* attn = (__bf16*)(ws + ((size_t)24 << 20));   // 4 MB  [S][E] bf16

    k_prep<<<dim3(32, 32, 6), dim3(32, 8), 0, stream>>>(x, Wq, Wk, Wv, Wo, xb, wt);
    k_gemm_qkv<<<dim3(E_DIM / 128, S_LEN / 128, 3), 256, 0, stream>>>(xb, wt, bq, bk, bv, qkv);
    k_attn<<<dim3(512), 256, 0, stream>>>(
        qkv, qkv + (size_t)NH * S_LEN * HD, qkv + (size_t)2 * NH * S_LEN * HD, attn);
    k_gemm_out<<<dim3(E_DIM / 128, S_LEN / 64), 256, 0, stream>>>(
        attn, wt + (size_t)3 * E_DIM * E_DIM, bo, out);
}